// Round 1
// baseline (3324.867 us; speedup 1.0000x reference)
//
#include <hip/hip_runtime.h>
#include <hip/hip_bf16.h>
#include <math.h>

// Problem constants (match reference)
#define B_   1024
#define L_   50
#define E_   20
#define N_   20
#define WD_  300
#define ED_  100
#define MD_  400
#define QD_  200
#define H_   20
#define DK_  20

// ---------------------------------------------------------------------------
// K1: h = tanh(word_embedding @ Ww1 + bw1)   [B*L,300]@[300,100]
// 4 rows per block so each Ww1 load feeds 4 FMAs.
// ---------------------------------------------------------------------------
__global__ __launch_bounds__(128) void k_word_lin(const float* __restrict__ we,
                                                  const float* __restrict__ Ww1,
                                                  const float* __restrict__ bw1,
                                                  float* __restrict__ h) {
    int row0 = blockIdx.x * 4;
    __shared__ float xs[4][WD_];
    int t = threadIdx.x;
    for (int i = t; i < 4 * WD_; i += 128)
        xs[i / WD_][i % WD_] = we[(size_t)row0 * WD_ + i];
    __syncthreads();
    if (t < 100) {
        float a0 = bw1[t], a1 = a0, a2 = a0, a3 = a0;
        for (int k = 0; k < WD_; ++k) {
            float w = Ww1[k * 100 + t];
            a0 = fmaf(xs[0][k], w, a0);
            a1 = fmaf(xs[1][k], w, a1);
            a2 = fmaf(xs[2][k], w, a2);
            a3 = fmaf(xs[3][k], w, a3);
        }
        h[(size_t)(row0 + 0) * 100 + t] = tanhf(a0);
        h[(size_t)(row0 + 1) * 100 + t] = tanhf(a1);
        h[(size_t)(row0 + 2) * 100 + t] = tanhf(a2);
        h[(size_t)(row0 + 3) * 100 + t] = tanhf(a3);
    }
}

// ---------------------------------------------------------------------------
// K2: fused MHSA per batch row b; loops 20 heads; writes tanh'd mh [B,L,400].
// q/k/v never materialized in global memory.
// LDS = 10000(hs bf16) + 24000(ws) + 12600(qkv) + 10600(ss) = 57.2 KB
// ---------------------------------------------------------------------------
__global__ __launch_bounds__(256) void k_mhsa(const float* __restrict__ h,
                                              const float* __restrict__ Wq, const float* __restrict__ bq,
                                              const float* __restrict__ Wk, const float* __restrict__ bk,
                                              const float* __restrict__ Wv, const float* __restrict__ bv,
                                              float* __restrict__ mh) {
    int b = blockIdx.x;
    __shared__ __hip_bfloat16 hs[L_][100];
    __shared__ float ws[3][100][20];
    __shared__ float qs[L_][21], ks[L_][21], vs[L_][21];
    __shared__ float ss[L_][53];
    int t = threadIdx.x;
    for (int i = t; i < L_ * 100; i += 256)
        hs[i / 100][i % 100] = __float2bfloat16(h[(size_t)b * L_ * 100 + i]);
    for (int hd = 0; hd < H_; ++hd) {
        __syncthreads();  // protects vs/ws reuse from previous iteration's readers
        for (int i = t; i < 100 * 20; i += 256) {
            int k = i / 20, j = i % 20;
            int col = hd * DK_ + j;
            ws[0][k][j] = Wq[k * MD_ + col];
            ws[1][k][j] = Wk[k * MD_ + col];
            ws[2][k][j] = Wv[k * MD_ + col];
        }
        __syncthreads();
        if (t < 200) {
            int j  = t % DK_;
            int l0 = (t / DK_) * 5;
            float aq[5], ak[5], av[5];
            float bqv = bq[hd * DK_ + j], bkv = bk[hd * DK_ + j], bvv = bv[hd * DK_ + j];
            #pragma unroll
            for (int r = 0; r < 5; ++r) { aq[r] = bqv; ak[r] = bkv; av[r] = bvv; }
            for (int k = 0; k < 100; ++k) {
                float wqv = ws[0][k][j], wkv = ws[1][k][j], wvv = ws[2][k][j];
                #pragma unroll
                for (int r = 0; r < 5; ++r) {
                    float hv = __bfloat162float(hs[l0 + r][k]);
                    aq[r] = fmaf(hv, wqv, aq[r]);
                    ak[r] = fmaf(hv, wkv, ak[r]);
                    av[r] = fmaf(hv, wvv, av[r]);
                }
            }
            #pragma unroll
            for (int r = 0; r < 5; ++r) {
                qs[l0 + r][j] = aq[r]; ks[l0 + r][j] = ak[r]; vs[l0 + r][j] = av[r];
            }
        }
        __syncthreads();
        const float scale = 0.22360679774997896f;  // 1/sqrt(20)
        for (int i = t; i < L_ * L_; i += 256) {
            int l = i / L_, m = i % L_;
            float a = 0.f;
            #pragma unroll
            for (int j = 0; j < DK_; ++j) a = fmaf(qs[l][j], ks[m][j], a);
            ss[l][m] = a * scale;
        }
        __syncthreads();
        if (t < L_) {
            float mx = -1e30f;
            for (int m = 0; m < L_; ++m) mx = fmaxf(mx, ss[t][m]);
            float sum = 0.f;
            for (int m = 0; m < L_; ++m) { float e = expf(ss[t][m] - mx); ss[t][m] = e; sum += e; }
            float inv = 1.f / sum;
            for (int m = 0; m < L_; ++m) ss[t][m] *= inv;
        }
        __syncthreads();
        for (int i = t; i < L_ * DK_; i += 256) {
            int l = i / DK_, j = i % DK_;
            float a = 0.f;
            for (int m = 0; m < L_; ++m) a = fmaf(ss[l][m], vs[m][j], a);
            mh[((size_t)b * L_ + l) * MD_ + hd * DK_ + j] = tanhf(a);
        }
    }
}

// ---------------------------------------------------------------------------
// K3: word additive attention. Register-tiled so Wwa is streamed ONCE per
// block (naive order would re-read Wwa 50x = 16 GB of L2 traffic).
// thread tile: 5 rows x 8 cols; 250/256 threads active.
// ---------------------------------------------------------------------------
__global__ __launch_bounds__(256) void k_word_att(const float* __restrict__ mh,
                                                  const float* __restrict__ Wwa,
                                                  const float* __restrict__ bwa,
                                                  const float* __restrict__ qwa,
                                                  float* __restrict__ word_rep) {
    int b = blockIdx.x;
    __shared__ __hip_bfloat16 mhs[L_][MD_];   // 40 KB
    __shared__ float att[L_];
    __shared__ float alpha_s[L_];
    int t = threadIdx.x;
    for (int i = t; i < L_ * MD_; i += 256)
        mhs[i / MD_][i % MD_] = __float2bfloat16(mh[(size_t)b * L_ * MD_ + i]);
    if (t < L_) att[t] = 0.f;
    __syncthreads();
    int rg = t / 25, cg = t % 25;
    if (rg < 10) {
        float acc[5][8];
        #pragma unroll
        for (int c = 0; c < 8; ++c) {
            float bv = bwa[cg * 8 + c];
            #pragma unroll
            for (int r = 0; r < 5; ++r) acc[r][c] = bv;
        }
        const float* Wp = Wwa + cg * 8;
        for (int d = 0; d < MD_; ++d) {
            float4 w0 = *(const float4*)(Wp + (size_t)d * QD_);
            float4 w1 = *(const float4*)(Wp + (size_t)d * QD_ + 4);
            float wv[8];
            wv[0] = w0.x; wv[1] = w0.y; wv[2] = w0.z; wv[3] = w0.w;
            wv[4] = w1.x; wv[5] = w1.y; wv[6] = w1.z; wv[7] = w1.w;
            #pragma unroll
            for (int r = 0; r < 5; ++r) {
                float xv = __bfloat162float(mhs[rg * 5 + r][d]);
                #pragma unroll
                for (int c = 0; c < 8; ++c) acc[r][c] = fmaf(xv, wv[c], acc[r][c]);
            }
        }
        #pragma unroll
        for (int r = 0; r < 5; ++r) {
            float pp = 0.f;
            #pragma unroll
            for (int c = 0; c < 8; ++c)
                pp = fmaf(tanhf(acc[r][c]), qwa[cg * 8 + c], pp);
            atomicAdd(&att[rg * 5 + r], pp);
        }
    }
    __syncthreads();
    if (t == 0) {
        float mx = -1e30f;
        for (int l = 0; l < L_; ++l) mx = fmaxf(mx, att[l]);
        float s = 0.f;
        for (int l = 0; l < L_; ++l) { float e = expf(att[l] - mx); alpha_s[l] = e; s += e; }
        float inv = 1.f / s;
        for (int l = 0; l < L_; ++l) alpha_s[l] *= inv;
    }
    __syncthreads();
    for (int d = t; d < MD_; d += 256) {
        float a = 0.f;
        for (int l = 0; l < L_; ++l)
            a = fmaf(alpha_s[l], __bfloat162float(mhs[l][d]), a);
        word_rep[(size_t)b * MD_ + d] = a;
    }
}

// ---------------------------------------------------------------------------
// K4: category / subcategory MLP: tanh(linear(linear(emb[idx]))) (no act between)
// ---------------------------------------------------------------------------
__global__ __launch_bounds__(128) void k_catsub(const float* __restrict__ emb,
                                                const float* __restrict__ W1, const float* __restrict__ b1,
                                                const float* __restrict__ W2, const float* __restrict__ b2,
                                                const int* __restrict__ idx, float* __restrict__ rep) {
    int b = blockIdx.x;
    __shared__ float es[100], h1[100];
    int t = threadIdx.x;
    int id = idx[b];
    if (t < 100) es[t] = emb[(size_t)id * 100 + t];
    __syncthreads();
    if (t < 100) {
        float a = b1[t];
        for (int k = 0; k < 100; ++k) a = fmaf(es[k], W1[k * 100 + t], a);
        h1[t] = a;
    }
    __syncthreads();
    for (int m = t; m < MD_; m += 128) {
        float a = b2[m];
        for (int k = 0; k < 100; ++k) a = fmaf(h1[k], W2[k * MD_ + m], a);
        rep[(size_t)b * MD_ + m] = tanhf(a);
    }
}

// ---------------------------------------------------------------------------
// K5: fused KGAT per 2 (b,e) groups (40 neighbor rows).
//   Y[40][400] = [NE|NR] @ A1[100:300]  (register-tiled 4x16 per thread)
//   att = relu(Y + ent@A1[0:100] + a1b) @ A2 -> softmax -> agg -> he
// A1 split avoids 98->67 GFLOP; fusion avoids a 655 MB intermediate.
// LDS ~= 37 KB -> 4 blocks/CU.
// ---------------------------------------------------------------------------
__global__ __launch_bounds__(256) void k_kgat(const float* __restrict__ ent_emb,
                                              const float* __restrict__ ne, const float* __restrict__ nr,
                                              const float* __restrict__ A1, const float* __restrict__ a1b,
                                              const float* __restrict__ A2,
                                              const float* __restrict__ We1, const float* __restrict__ be1,
                                              float* __restrict__ he) {
    __shared__ float xs[40][200];     // 32 KB: [NE|NR] rows for 2 groups
    __shared__ float ents[2][ED_];
    __shared__ float hA[2][MD_];
    __shared__ float att[40];
    __shared__ float alpha_s[40];
    __shared__ float agg[2][ED_];
    __shared__ float gmx[2], ginv[2];
    int t = threadIdx.x;
    int ge0 = blockIdx.x * 2;
    for (int i = t; i < 40 * 200; i += 256) {
        int row = i / 200, k = i % 200;
        int g = row / N_, n = row % N_;
        size_t base = ((size_t)(ge0 + g) * N_ + n) * ED_;
        xs[row][k] = (k < ED_) ? ne[base + k] : nr[base + k - ED_];
    }
    for (int i = t; i < 2 * ED_; i += 256)
        ents[i / ED_][i % ED_] = ent_emb[(size_t)ge0 * ED_ + i];
    if (t < 40) att[t] = 0.f;
    __syncthreads();
    // hA[g][c] = ents[g] @ A1[0:100]
    for (int i = t; i < 2 * MD_; i += 256) {
        int g = i / MD_, c = i % MD_;
        float a = 0.f;
        for (int k = 0; k < ED_; ++k) a = fmaf(ents[g][k], A1[k * MD_ + c], a);
        hA[g][c] = a;
    }
    __syncthreads();
    float acc[4][16];
    #pragma unroll
    for (int r = 0; r < 4; ++r)
        #pragma unroll
        for (int c = 0; c < 16; ++c) acc[r][c] = 0.f;
    int rg = t / 25, cg = t % 25;
    if (rg < 10) {
        const float* Wp = A1 + ED_ * MD_ + cg * 16;   // rows 100..299
        for (int k = 0; k < 200; ++k) {
            const float* wrow = Wp + (size_t)k * MD_;
            float4 w0 = *(const float4*)(wrow);
            float4 w1 = *(const float4*)(wrow + 4);
            float4 w2 = *(const float4*)(wrow + 8);
            float4 w3 = *(const float4*)(wrow + 12);
            float wv[16];
            wv[0]=w0.x;  wv[1]=w0.y;  wv[2]=w0.z;  wv[3]=w0.w;
            wv[4]=w1.x;  wv[5]=w1.y;  wv[6]=w1.z;  wv[7]=w1.w;
            wv[8]=w2.x;  wv[9]=w2.y;  wv[10]=w2.z; wv[11]=w2.w;
            wv[12]=w3.x; wv[13]=w3.y; wv[14]=w3.z; wv[15]=w3.w;
            #pragma unroll
            for (int r = 0; r < 4; ++r) {
                float xv = xs[rg * 4 + r][k];
                #pragma unroll
                for (int c = 0; c < 16; ++c) acc[r][c] = fmaf(xv, wv[c], acc[r][c]);
            }
        }
        #pragma unroll
        for (int r = 0; r < 4; ++r) {
            int row = rg * 4 + r;
            int g = (row >= N_) ? 1 : 0;
            float pp = 0.f;
            #pragma unroll
            for (int c = 0; c < 16; ++c) {
                int col = cg * 16 + c;
                float y = acc[r][c] + hA[g][col] + a1b[col];
                pp = fmaf(fmaxf(y, 0.f), A2[col], pp);
            }
            atomicAdd(&att[row], pp);   // a2b dropped: softmax shift-invariant
        }
    }
    __syncthreads();
    if (t < 2) {
        float mx = -1e30f;
        for (int n = 0; n < N_; ++n) mx = fmaxf(mx, att[t * N_ + n]);
        float s = 0.f;
        for (int n = 0; n < N_; ++n) s += expf(att[t * N_ + n] - mx);
        gmx[t] = mx; ginv[t] = 1.f / s;
    }
    __syncthreads();
    if (t < 40) alpha_s[t] = expf(att[t] - gmx[t / N_]) * ginv[t / N_];
    __syncthreads();
    for (int i = t; i < 2 * ED_; i += 256) {
        int g = i / ED_, d = i % ED_;
        float a = 0.f;
        for (int n = 0; n < N_; ++n)
            a = fmaf(alpha_s[g * N_ + n], xs[g * N_ + n][d], a);
        agg[g][d] = a;
    }
    __syncthreads();
    // he = tanh([ent, agg] @ We1 + be1)
    for (int i = t; i < 2 * ED_; i += 256) {
        int g = i / ED_, j = i % ED_;
        float a = be1[j];
        for (int k = 0; k < ED_; ++k) a = fmaf(ents[g][k], We1[k * ED_ + j], a);
        for (int d = 0; d < ED_; ++d) a = fmaf(agg[g][d], We1[(ED_ + d) * ED_ + j], a);
        he[(size_t)(ge0 + g) * ED_ + j] = tanhf(a);
    }
}

// ---------------------------------------------------------------------------
// K6: entity_rep = tanh(relu(mean_e(he) @ Wg + bg))
// (additive attn over identical rows collapses exactly to the row: Wea/bea/qea unused)
// ---------------------------------------------------------------------------
__global__ __launch_bounds__(128) void k_entity(const float* __restrict__ he,
                                                const float* __restrict__ Wg, const float* __restrict__ bg,
                                                float* __restrict__ entity_rep) {
    int b = blockIdx.x;
    __shared__ float mean_s[ED_];
    int t = threadIdx.x;
    if (t < ED_) {
        float a = 0.f;
        for (int e = 0; e < E_; ++e) a += he[((size_t)b * E_ + e) * ED_ + t];
        mean_s[t] = a * (1.f / E_);
    }
    __syncthreads();
    for (int m = t; m < MD_; m += 128) {
        float a = bg[m];
        for (int k = 0; k < ED_; ++k) a = fmaf(mean_s[k], Wg[k * MD_ + m], a);
        entity_rep[(size_t)b * MD_ + m] = tanhf(fmaxf(a, 0.f));
    }
}

// ---------------------------------------------------------------------------
// K7: fuse 4 views via additive attention -> pre-BN output into d_out
// ---------------------------------------------------------------------------
__global__ __launch_bounds__(256) void k_fuse(const float* __restrict__ wr, const float* __restrict__ er,
                                              const float* __restrict__ cr, const float* __restrict__ sr,
                                              const float* __restrict__ Wfa, const float* __restrict__ bfa,
                                              const float* __restrict__ qfa, float* __restrict__ out_pre) {
    int b = blockIdx.x;
    __shared__ float reps[4][MD_];
    __shared__ float alpha_s[4];
    __shared__ float red[4][4];
    int t = threadIdx.x, wave = t >> 6, lane = t & 63;
    for (int i = t; i < MD_; i += 256) {
        reps[0][i] = wr[(size_t)b * MD_ + i];
        reps[1][i] = er[(size_t)b * MD_ + i];
        reps[2][i] = cr[(size_t)b * MD_ + i];
        reps[3][i] = sr[(size_t)b * MD_ + i];
    }
    __syncthreads();
    float p[4] = {0.f, 0.f, 0.f, 0.f};
    if (t < QD_) {
        float acc0 = bfa[t], acc1 = acc0, acc2 = acc0, acc3 = acc0;
        for (int d = 0; d < MD_; ++d) {
            float w = Wfa[d * QD_ + t];
            acc0 = fmaf(reps[0][d], w, acc0);
            acc1 = fmaf(reps[1][d], w, acc1);
            acc2 = fmaf(reps[2][d], w, acc2);
            acc3 = fmaf(reps[3][d], w, acc3);
        }
        float qv = qfa[t];
        p[0] = tanhf(acc0) * qv; p[1] = tanhf(acc1) * qv;
        p[2] = tanhf(acc2) * qv; p[3] = tanhf(acc3) * qv;
    }
    #pragma unroll
    for (int i = 0; i < 4; ++i) {
        float v = p[i];
        for (int o = 32; o > 0; o >>= 1) v += __shfl_down(v, o);
        if (lane == 0) red[i][wave] = v;
    }
    __syncthreads();
    if (t == 0) {
        float a4[4]; float mx = -1e30f;
        #pragma unroll
        for (int i = 0; i < 4; ++i) { a4[i] = red[i][0] + red[i][1] + red[i][2] + red[i][3]; mx = fmaxf(mx, a4[i]); }
        float s = 0.f;
        #pragma unroll
        for (int i = 0; i < 4; ++i) { a4[i] = expf(a4[i] - mx); s += a4[i]; }
        float inv = 1.f / s;
        #pragma unroll
        for (int i = 0; i < 4; ++i) alpha_s[i] = a4[i] * inv;
    }
    __syncthreads();
    for (int m = t; m < MD_; m += 256)
        out_pre[(size_t)b * MD_ + m] = alpha_s[0] * reps[0][m] + alpha_s[1] * reps[1][m]
                                     + alpha_s[2] * reps[2][m] + alpha_s[3] * reps[3][m];
}

// ---------------------------------------------------------------------------
// K8: batchnorm over batch axis, in-place on d_out (reads cached in regs first).
// jnp.var is biased (/B).
// ---------------------------------------------------------------------------
__global__ __launch_bounds__(256) void k_bn(float* __restrict__ x,
                                            const float* __restrict__ gamma,
                                            const float* __restrict__ beta) {
    int m = blockIdx.x;
    int t = threadIdx.x, wave = t >> 6, lane = t & 63;
    __shared__ float red1[4], red2[4];
    float v[4];
    float s1 = 0.f, s2 = 0.f;
    #pragma unroll
    for (int i = 0; i < 4; ++i) {
        v[i] = x[(size_t)(t + i * 256) * MD_ + m];
        s1 += v[i];
        s2 = fmaf(v[i], v[i], s2);
    }
    for (int o = 32; o > 0; o >>= 1) { s1 += __shfl_down(s1, o); s2 += __shfl_down(s2, o); }
    if (lane == 0) { red1[wave] = s1; red2[wave] = s2; }
    __syncthreads();
    float mean = (red1[0] + red1[1] + red1[2] + red1[3]) * (1.f / 1024.f);
    float var  = (red2[0] + red2[1] + red2[2] + red2[3]) * (1.f / 1024.f) - mean * mean;
    float scale = rsqrtf(var + 1e-5f) * gamma[m];
    float bb = beta[m];
    #pragma unroll
    for (int i = 0; i < 4; ++i)
        x[(size_t)(t + i * 256) * MD_ + m] = (v[i] - mean) * scale + bb;
}

// ---------------------------------------------------------------------------
extern "C" void kernel_launch(void* const* d_in, const int* in_sizes, int n_in,
                              void* d_out, int out_size, void* d_ws, size_t ws_size,
                              hipStream_t stream) {
    const float* word_emb = (const float*)d_in[0];
    const float* ent_emb  = (const float*)d_in[1];
    const float* ne       = (const float*)d_in[2];
    const float* nr       = (const float*)d_in[3];
    const float* emb_c    = (const float*)d_in[4];
    const float* Wc1 = (const float*)d_in[5];
    const float* bc1 = (const float*)d_in[6];
    const float* Wc2 = (const float*)d_in[7];
    const float* bc2 = (const float*)d_in[8];
    const float* emb_s = (const float*)d_in[9];
    const float* Ws1 = (const float*)d_in[10];
    const float* bs1 = (const float*)d_in[11];
    const float* Ws2 = (const float*)d_in[12];
    const float* bs2 = (const float*)d_in[13];
    const float* Ww1 = (const float*)d_in[14];
    const float* bw1 = (const float*)d_in[15];
    const float* Wq  = (const float*)d_in[16];
    const float* bq  = (const float*)d_in[17];
    const float* Wk  = (const float*)d_in[18];
    const float* bk  = (const float*)d_in[19];
    const float* Wv  = (const float*)d_in[20];
    const float* bv  = (const float*)d_in[21];
    const float* Wwa = (const float*)d_in[22];
    const float* bwa = (const float*)d_in[23];
    const float* qwa = (const float*)d_in[24];
    const float* A1  = (const float*)d_in[25];
    const float* a1b = (const float*)d_in[26];
    const float* A2  = (const float*)d_in[27];
    // d_in[28] = a2b: constant shift before softmax, drops out
    const float* We1 = (const float*)d_in[29];
    const float* be1 = (const float*)d_in[30];
    const float* Wg  = (const float*)d_in[31];
    const float* bg  = (const float*)d_in[32];
    // d_in[33..35] = Wea/bea/qea: eliminated (additive attn over identical rows)
    const float* Wfa = (const float*)d_in[36];
    const float* bfa = (const float*)d_in[37];
    const float* qfa = (const float*)d_in[38];
    const float* gamma = (const float*)d_in[39];
    const float* beta  = (const float*)d_in[40];
    const int* cat_idx = (const int*)d_in[41];
    const int* sub_idx = (const int*)d_in[42];

    // workspace layout (floats); total 28,876,800 f32 = 115.6 MB required
    float* ws = (float*)d_ws;
    float* mh         = ws;                       // B*L*400 = 20,480,000
    float* h_word     = mh + (size_t)B_ * L_ * MD_;      // B*L*100 =  5,120,000
    float* word_rep   = h_word + (size_t)B_ * L_ * 100;  // B*400
    float* cat_rep    = word_rep + (size_t)B_ * MD_;
    float* sub_rep    = cat_rep + (size_t)B_ * MD_;
    float* he         = sub_rep + (size_t)B_ * MD_;      // B*E*100 = 2,048,000
    float* entity_rep = he + (size_t)B_ * E_ * ED_;
    float* out = (float*)d_out;

    k_word_lin<<<(B_ * L_) / 4, 128, 0, stream>>>(word_emb, Ww1, bw1, h_word);
    k_mhsa<<<B_, 256, 0, stream>>>(h_word, Wq, bq, Wk, bk, Wv, bv, mh);
    k_word_att<<<B_, 256, 0, stream>>>(mh, Wwa, bwa, qwa, word_rep);
    k_catsub<<<B_, 128, 0, stream>>>(emb_c, Wc1, bc1, Wc2, bc2, cat_idx, cat_rep);
    k_catsub<<<B_, 128, 0, stream>>>(emb_s, Ws1, bs1, Ws2, bs2, sub_idx, sub_rep);
    k_kgat<<<(B_ * E_) / 2, 256, 0, stream>>>(ent_emb, ne, nr, A1, a1b, A2, We1, be1, he);
    k_entity<<<B_, 128, 0, stream>>>(he, Wg, bg, entity_rep);
    k_fuse<<<B_, 256, 0, stream>>>(word_rep, entity_rep, cat_rep, sub_rep, Wfa, bfa, qfa, out);
    k_bn<<<MD_, 256, 0, stream>>>(out, gamma, beta);
}

// Round 2
// 1721.520 us; speedup vs baseline: 1.9314x; 1.9314x over previous
//
#include <hip/hip_runtime.h>
#include <hip/hip_bf16.h>
#include <math.h>

// Problem constants (match reference)
#define B_   1024
#define L_   50
#define E_   20
#define N_   20
#define WD_  300
#define ED_  100
#define MD_  400
#define QD_  200
#define H_   20
#define DK_  20

// KGAT-MFMA geometry
#define G_    4      // (b,e) groups per block
#define MROWS 80     // G_*N_
#define KP    320    // K=300 padded to 10*32
#define NT_   25     // N tiles (400/16)
#define KS_   10     // K steps (320/32)

typedef __bf16 bf8_t __attribute__((ext_vector_type(8)));
typedef float  f32x4 __attribute__((ext_vector_type(4)));

__device__ __forceinline__ unsigned short f2bf(float f) {
    __hip_bfloat16 h = __float2bfloat16(f);
    return *reinterpret_cast<unsigned short*>(&h);
}
__device__ __forceinline__ float bf2f(unsigned short u) {
    return __uint_as_float(((unsigned int)u) << 16);
}
// swizzled ushort index for X_lds element (row r, col k): 16B-granule XOR swizzle
__device__ __forceinline__ int swz(int r, int k) {
    return r * KP + ((((k >> 3) ^ (r & 7)) << 3) | (k & 7));
}

// ---------------------------------------------------------------------------
// K1: h = tanh(word_embedding @ Ww1 + bw1)   [B*L,300]@[300,100]
// ---------------------------------------------------------------------------
__global__ __launch_bounds__(128) void k_word_lin(const float* __restrict__ we,
                                                  const float* __restrict__ Ww1,
                                                  const float* __restrict__ bw1,
                                                  float* __restrict__ h) {
    int row0 = blockIdx.x * 4;
    __shared__ float xs[4][WD_];
    int t = threadIdx.x;
    for (int i = t; i < 4 * WD_; i += 128)
        xs[i / WD_][i % WD_] = we[(size_t)row0 * WD_ + i];
    __syncthreads();
    if (t < 100) {
        float a0 = bw1[t], a1 = a0, a2 = a0, a3 = a0;
        for (int k = 0; k < WD_; ++k) {
            float w = Ww1[k * 100 + t];
            a0 = fmaf(xs[0][k], w, a0);
            a1 = fmaf(xs[1][k], w, a1);
            a2 = fmaf(xs[2][k], w, a2);
            a3 = fmaf(xs[3][k], w, a3);
        }
        h[(size_t)(row0 + 0) * 100 + t] = tanhf(a0);
        h[(size_t)(row0 + 1) * 100 + t] = tanhf(a1);
        h[(size_t)(row0 + 2) * 100 + t] = tanhf(a2);
        h[(size_t)(row0 + 3) * 100 + t] = tanhf(a3);
    }
}

// ---------------------------------------------------------------------------
// K2: fused MHSA per batch row b (unchanged from R1)
// ---------------------------------------------------------------------------
__global__ __launch_bounds__(256) void k_mhsa(const float* __restrict__ h,
                                              const float* __restrict__ Wq, const float* __restrict__ bq,
                                              const float* __restrict__ Wk, const float* __restrict__ bk,
                                              const float* __restrict__ Wv, const float* __restrict__ bv,
                                              float* __restrict__ mh) {
    int b = blockIdx.x;
    __shared__ __hip_bfloat16 hs[L_][100];
    __shared__ float ws[3][100][20];
    __shared__ float qs[L_][21], ks[L_][21], vs[L_][21];
    __shared__ float ss[L_][53];
    int t = threadIdx.x;
    for (int i = t; i < L_ * 100; i += 256)
        hs[i / 100][i % 100] = __float2bfloat16(h[(size_t)b * L_ * 100 + i]);
    for (int hd = 0; hd < H_; ++hd) {
        __syncthreads();
        for (int i = t; i < 100 * 20; i += 256) {
            int k = i / 20, j = i % 20;
            int col = hd * DK_ + j;
            ws[0][k][j] = Wq[k * MD_ + col];
            ws[1][k][j] = Wk[k * MD_ + col];
            ws[2][k][j] = Wv[k * MD_ + col];
        }
        __syncthreads();
        if (t < 200) {
            int j  = t % DK_;
            int l0 = (t / DK_) * 5;
            float aq[5], ak[5], av[5];
            float bqv = bq[hd * DK_ + j], bkv = bk[hd * DK_ + j], bvv = bv[hd * DK_ + j];
            #pragma unroll
            for (int r = 0; r < 5; ++r) { aq[r] = bqv; ak[r] = bkv; av[r] = bvv; }
            for (int k = 0; k < 100; ++k) {
                float wqv = ws[0][k][j], wkv = ws[1][k][j], wvv = ws[2][k][j];
                #pragma unroll
                for (int r = 0; r < 5; ++r) {
                    float hv = __bfloat162float(hs[l0 + r][k]);
                    aq[r] = fmaf(hv, wqv, aq[r]);
                    ak[r] = fmaf(hv, wkv, ak[r]);
                    av[r] = fmaf(hv, wvv, av[r]);
                }
            }
            #pragma unroll
            for (int r = 0; r < 5; ++r) {
                qs[l0 + r][j] = aq[r]; ks[l0 + r][j] = ak[r]; vs[l0 + r][j] = av[r];
            }
        }
        __syncthreads();
        const float scale = 0.22360679774997896f;
        for (int i = t; i < L_ * L_; i += 256) {
            int l = i / L_, m = i % L_;
            float a = 0.f;
            #pragma unroll
            for (int j = 0; j < DK_; ++j) a = fmaf(qs[l][j], ks[m][j], a);
            ss[l][m] = a * scale;
        }
        __syncthreads();
        if (t < L_) {
            float mx = -1e30f;
            for (int m = 0; m < L_; ++m) mx = fmaxf(mx, ss[t][m]);
            float sum = 0.f;
            for (int m = 0; m < L_; ++m) { float e = expf(ss[t][m] - mx); ss[t][m] = e; sum += e; }
            float inv = 1.f / sum;
            for (int m = 0; m < L_; ++m) ss[t][m] *= inv;
        }
        __syncthreads();
        for (int i = t; i < L_ * DK_; i += 256) {
            int l = i / DK_, j = i % DK_;
            float a = 0.f;
            for (int m = 0; m < L_; ++m) a = fmaf(ss[l][m], vs[m][j], a);
            mh[((size_t)b * L_ + l) * MD_ + hd * DK_ + j] = tanhf(a);
        }
    }
}

// ---------------------------------------------------------------------------
// K3: word additive attention (unchanged from R1)
// ---------------------------------------------------------------------------
__global__ __launch_bounds__(256) void k_word_att(const float* __restrict__ mh,
                                                  const float* __restrict__ Wwa,
                                                  const float* __restrict__ bwa,
                                                  const float* __restrict__ qwa,
                                                  float* __restrict__ word_rep) {
    int b = blockIdx.x;
    __shared__ __hip_bfloat16 mhs[L_][MD_];
    __shared__ float att[L_];
    __shared__ float alpha_s[L_];
    int t = threadIdx.x;
    for (int i = t; i < L_ * MD_; i += 256)
        mhs[i / MD_][i % MD_] = __float2bfloat16(mh[(size_t)b * L_ * MD_ + i]);
    if (t < L_) att[t] = 0.f;
    __syncthreads();
    int rg = t / 25, cg = t % 25;
    if (rg < 10) {
        float acc[5][8];
        #pragma unroll
        for (int c = 0; c < 8; ++c) {
            float bv = bwa[cg * 8 + c];
            #pragma unroll
            for (int r = 0; r < 5; ++r) acc[r][c] = bv;
        }
        const float* Wp = Wwa + cg * 8;
        for (int d = 0; d < MD_; ++d) {
            float4 w0 = *(const float4*)(Wp + (size_t)d * QD_);
            float4 w1 = *(const float4*)(Wp + (size_t)d * QD_ + 4);
            float wv[8];
            wv[0] = w0.x; wv[1] = w0.y; wv[2] = w0.z; wv[3] = w0.w;
            wv[4] = w1.x; wv[5] = w1.y; wv[6] = w1.z; wv[7] = w1.w;
            #pragma unroll
            for (int r = 0; r < 5; ++r) {
                float xv = __bfloat162float(mhs[rg * 5 + r][d]);
                #pragma unroll
                for (int c = 0; c < 8; ++c) acc[r][c] = fmaf(xv, wv[c], acc[r][c]);
            }
        }
        #pragma unroll
        for (int r = 0; r < 5; ++r) {
            float pp = 0.f;
            #pragma unroll
            for (int c = 0; c < 8; ++c)
                pp = fmaf(tanhf(acc[r][c]), qwa[cg * 8 + c], pp);
            atomicAdd(&att[rg * 5 + r], pp);
        }
    }
    __syncthreads();
    if (t == 0) {
        float mx = -1e30f;
        for (int l = 0; l < L_; ++l) mx = fmaxf(mx, att[l]);
        float s = 0.f;
        for (int l = 0; l < L_; ++l) { float e = expf(att[l] - mx); alpha_s[l] = e; s += e; }
        float inv = 1.f / s;
        for (int l = 0; l < L_; ++l) alpha_s[l] *= inv;
    }
    __syncthreads();
    for (int d = t; d < MD_; d += 256) {
        float a = 0.f;
        for (int l = 0; l < L_; ++l)
            a = fmaf(alpha_s[l], __bfloat162float(mhs[l][d]), a);
        word_rep[(size_t)b * MD_ + d] = a;
    }
}

// ---------------------------------------------------------------------------
// K4: category / subcategory MLP (unchanged from R1)
// ---------------------------------------------------------------------------
__global__ __launch_bounds__(128) void k_catsub(const float* __restrict__ emb,
                                                const float* __restrict__ W1, const float* __restrict__ b1,
                                                const float* __restrict__ W2, const float* __restrict__ b2,
                                                const int* __restrict__ idx, float* __restrict__ rep) {
    int b = blockIdx.x;
    __shared__ float es[100], h1[100];
    int t = threadIdx.x;
    int id = idx[b];
    if (t < 100) es[t] = emb[(size_t)id * 100 + t];
    __syncthreads();
    if (t < 100) {
        float a = b1[t];
        for (int k = 0; k < 100; ++k) a = fmaf(es[k], W1[k * 100 + t], a);
        h1[t] = a;
    }
    __syncthreads();
    for (int m = t; m < MD_; m += 128) {
        float a = b2[m];
        for (int k = 0; k < 100; ++k) a = fmaf(h1[k], W2[k * MD_ + m], a);
        rep[(size_t)b * MD_ + m] = tanhf(a);
    }
}

// ---------------------------------------------------------------------------
// K5a: pack A1 (f32 [300][400], zero-padded to K=320) into the exact
// mfma_f32_16x16x32_bf16 B-fragment layout: lane l of tile (nt,ks) holds
// B[k = ks*32 + (l>>4)*8 + j][n = nt*16 + (l&15)], j=0..7, 16B/lane.
// One-time 256 KB buffer -> every B-load in K5b is one coalesced dwordx4.
// ---------------------------------------------------------------------------
__global__ __launch_bounds__(64) void k_pack_A1(const float* __restrict__ A1,
                                                unsigned short* __restrict__ Bp) {
    int nt = blockIdx.x;        // 0..24
    int ks = blockIdx.y;        // 0..9
    int lane = threadIdx.x;     // 0..63
    int n  = nt * 16 + (lane & 15);
    int k0 = ks * 32 + (lane >> 4) * 8;
    unsigned short v[8];
    #pragma unroll
    for (int j = 0; j < 8; ++j) {
        int k = k0 + j;
        float f = (k < 300) ? A1[(size_t)k * MD_ + n] : 0.f;
        v[j] = f2bf(f);
    }
    unsigned short* dst = Bp + ((size_t)(nt * KS_ + ks) * 64 + lane) * 8;
    *(bf8_t*)dst = *(const bf8_t*)v;   // 16B store
}

// ---------------------------------------------------------------------------
// K5b: MFMA KGAT. Per block: G_=4 (b,e) groups -> X[80][320] bf16 in LDS
// (rows = [ent | ne | nr | 0-pad]; head-entity term folded into the GEMM).
// 5 waves; wave w owns N cols [w*80, w*80+80). acc = 5x5 16x16 tiles.
// X_lds uses a 16B-granule XOR swizzle (g ^= row&7) -> ds_read_b128 A-frag
// reads are 2-way (free) instead of 8-way conflicted.
// Epilogue fuses relu -> .A2 -> shfl-reduce -> softmax -> agg -> he.
// ---------------------------------------------------------------------------
__global__ __launch_bounds__(320) void k_kgat_mfma(const float* __restrict__ ent_emb,
                                                   const float* __restrict__ ne,
                                                   const float* __restrict__ nr,
                                                   const unsigned short* __restrict__ Bp,
                                                   const float* __restrict__ a1b,
                                                   const float* __restrict__ A2,
                                                   const float* __restrict__ We1,
                                                   const float* __restrict__ be1,
                                                   float* __restrict__ he) {
    __shared__ unsigned short Xs[MROWS * KP];   // 51.2 KB
    __shared__ float att_s[MROWS];
    __shared__ float alpha_s[MROWS];
    __shared__ float agg_s[G_][ED_];
    __shared__ float gmx[G_], ginv[G_];
    int t = threadIdx.x;
    int ge0 = blockIdx.x * G_;

    if (t < MROWS) att_s[t] = 0.f;
    const size_t nebase = (size_t)ge0 * N_ * ED_;
    // stage ne (cols 100..199) and nr (cols 200..299), coalesced reads
    for (int i = t; i < G_ * N_ * ED_; i += 320) {
        int r = i / ED_, d = i % ED_;
        Xs[swz(r, 100 + d)] = f2bf(ne[nebase + i]);
    }
    for (int i = t; i < G_ * N_ * ED_; i += 320) {
        int r = i / ED_, d = i % ED_;
        Xs[swz(r, 200 + d)] = f2bf(nr[nebase + i]);
    }
    // ent replicated across the 20 rows of its group (cols 0..99); L1-cached
    for (int i = t; i < G_ * N_ * ED_; i += 320) {
        int r = i / ED_, k = i % ED_, g = r / N_;
        Xs[swz(r, k)] = f2bf(ent_emb[(size_t)(ge0 + g) * ED_ + k]);
    }
    // zero pad cols 300..319
    for (int i = t; i < MROWS * 20; i += 320) {
        int r = i / 20, k = 300 + (i % 20);
        Xs[swz(r, k)] = 0;
    }
    __syncthreads();

    int wv = t >> 6, lane = t & 63;
    int lr = lane & 15, lq = lane >> 4;
    f32x4 acc[5][5];
    #pragma unroll
    for (int mi = 0; mi < 5; ++mi)
        #pragma unroll
        for (int nj = 0; nj < 5; ++nj)
            acc[mi][nj] = (f32x4){0.f, 0.f, 0.f, 0.f};

    for (int ks = 0; ks < KS_; ++ks) {
        bf8_t a[5], b[5];
        #pragma unroll
        for (int mi = 0; mi < 5; ++mi) {
            int r = mi * 16 + lr;
            int g = (ks * 4 + lq) ^ (r & 7);
            a[mi] = *(const bf8_t*)&Xs[r * KP + g * 8];
        }
        #pragma unroll
        for (int nj = 0; nj < 5; ++nj) {
            const unsigned short* p = Bp + ((size_t)((wv * 5 + nj) * KS_ + ks) * 64 + lane) * 8;
            b[nj] = *(const bf8_t*)p;
        }
        #pragma unroll
        for (int mi = 0; mi < 5; ++mi)
            #pragma unroll
            for (int nj = 0; nj < 5; ++nj)
                acc[mi][nj] = __builtin_amdgcn_mfma_f32_16x16x32_bf16(a[mi], b[nj], acc[mi][nj], 0, 0, 0);
    }

    // epilogue: att[row] += sum_c relu(Y + a1b[c]) * A2[c]
    float pr[5][4];
    #pragma unroll
    for (int mi = 0; mi < 5; ++mi)
        #pragma unroll
        for (int j = 0; j < 4; ++j) pr[mi][j] = 0.f;
    #pragma unroll
    for (int nj = 0; nj < 5; ++nj) {
        int col = wv * 80 + nj * 16 + lr;
        float a1bv = a1b[col], a2v = A2[col];
        #pragma unroll
        for (int mi = 0; mi < 5; ++mi) {
            #pragma unroll
            for (int j = 0; j < 4; ++j) {
                float y = acc[mi][nj][j] + a1bv;
                pr[mi][j] = fmaf(fmaxf(y, 0.f), a2v, pr[mi][j]);
            }
        }
    }
    #pragma unroll
    for (int mi = 0; mi < 5; ++mi) {
        #pragma unroll
        for (int j = 0; j < 4; ++j) {
            float v = pr[mi][j];
            v += __shfl_xor(v, 1); v += __shfl_xor(v, 2);
            v += __shfl_xor(v, 4); v += __shfl_xor(v, 8);
            if (lr == 0) atomicAdd(&att_s[mi * 16 + lq * 4 + j], v);
        }
    }
    __syncthreads();

    // softmax over the 20 neighbors of each group
    if (t < G_) {
        float mx = -1e30f;
        for (int n = 0; n < N_; ++n) mx = fmaxf(mx, att_s[t * N_ + n]);
        float s = 0.f;
        for (int n = 0; n < N_; ++n) s += expf(att_s[t * N_ + n] - mx);
        gmx[t] = mx; ginv[t] = 1.f / s;
    }
    __syncthreads();
    if (t < MROWS) alpha_s[t] = expf(att_s[t] - gmx[t / N_]) * ginv[t / N_];
    __syncthreads();

    // agg[g][d] = sum_n alpha * ne (read back from swizzled bf16 tile)
    for (int i = t; i < G_ * ED_; i += 320) {
        int g = i / ED_, d = i % ED_;
        float a = 0.f;
        for (int n = 0; n < N_; ++n) {
            int r = g * N_ + n;
            a = fmaf(alpha_s[r], bf2f(Xs[swz(r, 100 + d)]), a);
        }
        agg_s[g][d] = a;
    }
    __syncthreads();

    // he = tanh([ent, agg] @ We1 + be1)
    for (int i = t; i < G_ * ED_; i += 320) {
        int g = i / ED_, j = i % ED_;
        float a = be1[j];
        int r0 = g * N_;
        for (int k = 0; k < ED_; ++k)
            a = fmaf(bf2f(Xs[swz(r0, k)]), We1[k * ED_ + j], a);
        for (int d = 0; d < ED_; ++d)
            a = fmaf(agg_s[g][d], We1[(ED_ + d) * ED_ + j], a);
        he[(size_t)(ge0 + g) * ED_ + j] = tanhf(a);
    }
}

// ---------------------------------------------------------------------------
// K6: entity_rep = tanh(relu(mean_e(he) @ Wg + bg))  (unchanged)
// ---------------------------------------------------------------------------
__global__ __launch_bounds__(128) void k_entity(const float* __restrict__ he,
                                                const float* __restrict__ Wg, const float* __restrict__ bg,
                                                float* __restrict__ entity_rep) {
    int b = blockIdx.x;
    __shared__ float mean_s[ED_];
    int t = threadIdx.x;
    if (t < ED_) {
        float a = 0.f;
        for (int e = 0; e < E_; ++e) a += he[((size_t)b * E_ + e) * ED_ + t];
        mean_s[t] = a * (1.f / E_);
    }
    __syncthreads();
    for (int m = t; m < MD_; m += 128) {
        float a = bg[m];
        for (int k = 0; k < ED_; ++k) a = fmaf(mean_s[k], Wg[k * MD_ + m], a);
        entity_rep[(size_t)b * MD_ + m] = tanhf(fmaxf(a, 0.f));
    }
}

// ---------------------------------------------------------------------------
// K7: fuse 4 views via additive attention (unchanged)
// ---------------------------------------------------------------------------
__global__ __launch_bounds__(256) void k_fuse(const float* __restrict__ wr, const float* __restrict__ er,
                                              const float* __restrict__ cr, const float* __restrict__ sr,
                                              const float* __restrict__ Wfa, const float* __restrict__ bfa,
                                              const float* __restrict__ qfa, float* __restrict__ out_pre) {
    int b = blockIdx.x;
    __shared__ float reps[4][MD_];
    __shared__ float alpha_s[4];
    __shared__ float red[4][4];
    int t = threadIdx.x, wave = t >> 6, lane = t & 63;
    for (int i = t; i < MD_; i += 256) {
        reps[0][i] = wr[(size_t)b * MD_ + i];
        reps[1][i] = er[(size_t)b * MD_ + i];
        reps[2][i] = cr[(size_t)b * MD_ + i];
        reps[3][i] = sr[(size_t)b * MD_ + i];
    }
    __syncthreads();
    float p[4] = {0.f, 0.f, 0.f, 0.f};
    if (t < QD_) {
        float acc0 = bfa[t], acc1 = acc0, acc2 = acc0, acc3 = acc0;
        for (int d = 0; d < MD_; ++d) {
            float w = Wfa[d * QD_ + t];
            acc0 = fmaf(reps[0][d], w, acc0);
            acc1 = fmaf(reps[1][d], w, acc1);
            acc2 = fmaf(reps[2][d], w, acc2);
            acc3 = fmaf(reps[3][d], w, acc3);
        }
        float qv = qfa[t];
        p[0] = tanhf(acc0) * qv; p[1] = tanhf(acc1) * qv;
        p[2] = tanhf(acc2) * qv; p[3] = tanhf(acc3) * qv;
    }
    #pragma unroll
    for (int i = 0; i < 4; ++i) {
        float v = p[i];
        for (int o = 32; o > 0; o >>= 1) v += __shfl_down(v, o);
        if (lane == 0) red[i][wave] = v;
    }
    __syncthreads();
    if (t == 0) {
        float a4[4]; float mx = -1e30f;
        #pragma unroll
        for (int i = 0; i < 4; ++i) { a4[i] = red[i][0] + red[i][1] + red[i][2] + red[i][3]; mx = fmaxf(mx, a4[i]); }
        float s = 0.f;
        #pragma unroll
        for (int i = 0; i < 4; ++i) { a4[i] = expf(a4[i] - mx); s += a4[i]; }
        float inv = 1.f / s;
        #pragma unroll
        for (int i = 0; i < 4; ++i) alpha_s[i] = a4[i] * inv;
    }
    __syncthreads();
    for (int m = t; m < MD_; m += 256)
        out_pre[(size_t)b * MD_ + m] = alpha_s[0] * reps[0][m] + alpha_s[1] * reps[1][m]
                                     + alpha_s[2] * reps[2][m] + alpha_s[3] * reps[3][m];
}

// ---------------------------------------------------------------------------
// K8: batchnorm over batch axis (unchanged)
// ---------------------------------------------------------------------------
__global__ __launch_bounds__(256) void k_bn(float* __restrict__ x,
                                            const float* __restrict__ gamma,
                                            const float* __restrict__ beta) {
    int m = blockIdx.x;
    int t = threadIdx.x, wave = t >> 6, lane = t & 63;
    __shared__ float red1[4], red2[4];
    float v[4];
    float s1 = 0.f, s2 = 0.f;
    #pragma unroll
    for (int i = 0; i < 4; ++i) {
        v[i] = x[(size_t)(t + i * 256) * MD_ + m];
        s1 += v[i];
        s2 = fmaf(v[i], v[i], s2);
    }
    for (int o = 32; o > 0; o >>= 1) { s1 += __shfl_down(s1, o); s2 += __shfl_down(s2, o); }
    if (lane == 0) { red1[wave] = s1; red2[wave] = s2; }
    __syncthreads();
    float mean = (red1[0] + red1[1] + red1[2] + red1[3]) * (1.f / 1024.f);
    float var  = (red2[0] + red2[1] + red2[2] + red2[3]) * (1.f / 1024.f) - mean * mean;
    float scale = rsqrtf(var + 1e-5f) * gamma[m];
    float bb = beta[m];
    #pragma unroll
    for (int i = 0; i < 4; ++i)
        x[(size_t)(t + i * 256) * MD_ + m] = (v[i] - mean) * scale + bb;
}

// ---------------------------------------------------------------------------
extern "C" void kernel_launch(void* const* d_in, const int* in_sizes, int n_in,
                              void* d_out, int out_size, void* d_ws, size_t ws_size,
                              hipStream_t stream) {
    const float* word_emb = (const float*)d_in[0];
    const float* ent_emb  = (const float*)d_in[1];
    const float* ne       = (const float*)d_in[2];
    const float* nr       = (const float*)d_in[3];
    const float* emb_c    = (const float*)d_in[4];
    const float* Wc1 = (const float*)d_in[5];
    const float* bc1 = (const float*)d_in[6];
    const float* Wc2 = (const float*)d_in[7];
    const float* bc2 = (const float*)d_in[8];
    const float* emb_s = (const float*)d_in[9];
    const float* Ws1 = (const float*)d_in[10];
    const float* bs1 = (const float*)d_in[11];
    const float* Ws2 = (const float*)d_in[12];
    const float* bs2 = (const float*)d_in[13];
    const float* Ww1 = (const float*)d_in[14];
    const float* bw1 = (const float*)d_in[15];
    const float* Wq  = (const float*)d_in[16];
    const float* bq  = (const float*)d_in[17];
    const float* Wk  = (const float*)d_in[18];
    const float* bk  = (const float*)d_in[19];
    const float* Wv  = (const float*)d_in[20];
    const float* bv  = (const float*)d_in[21];
    const float* Wwa = (const float*)d_in[22];
    const float* bwa = (const float*)d_in[23];
    const float* qwa = (const float*)d_in[24];
    const float* A1  = (const float*)d_in[25];
    const float* a1b = (const float*)d_in[26];
    const float* A2  = (const float*)d_in[27];
    // d_in[28] = a2b: constant shift before softmax, drops out
    const float* We1 = (const float*)d_in[29];
    const float* be1 = (const float*)d_in[30];
    const float* Wg  = (const float*)d_in[31];
    const float* bg  = (const float*)d_in[32];
    // d_in[33..35] = Wea/bea/qea: eliminated (additive attn over identical rows)
    const float* Wfa = (const float*)d_in[36];
    const float* bfa = (const float*)d_in[37];
    const float* qfa = (const float*)d_in[38];
    const float* gamma = (const float*)d_in[39];
    const float* beta  = (const float*)d_in[40];
    const int* cat_idx = (const int*)d_in[41];
    const int* sub_idx = (const int*)d_in[42];

    // workspace layout (floats); ~117.4 MB total
    float* ws = (float*)d_ws;
    float* mh         = ws;                                   // B*L*400
    float* h_word     = mh + (size_t)B_ * L_ * MD_;           // B*L*100
    float* word_rep   = h_word + (size_t)B_ * L_ * 100;       // B*400
    float* cat_rep    = word_rep + (size_t)B_ * MD_;
    float* sub_rep    = cat_rep + (size_t)B_ * MD_;
    float* he         = sub_rep + (size_t)B_ * MD_;           // B*E*100
    float* entity_rep = he + (size_t)B_ * E_ * ED_;
    unsigned short* Bp = (unsigned short*)(entity_rep + (size_t)B_ * MD_);  // 25*10*512 bf16 = 256 KB
    float* out = (float*)d_out;

    k_pack_A1<<<dim3(NT_, KS_), 64, 0, stream>>>(A1, Bp);
    k_word_lin<<<(B_ * L_) / 4, 128, 0, stream>>>(word_emb, Ww1, bw1, h_word);
    k_mhsa<<<B_, 256, 0, stream>>>(h_word, Wq, bq, Wk, bk, Wv, bv, mh);
    k_word_att<<<B_, 256, 0, stream>>>(mh, Wwa, bwa, qwa, word_rep);
    k_catsub<<<B_, 128, 0, stream>>>(emb_c, Wc1, bc1, Wc2, bc2, cat_idx, cat_rep);
    k_catsub<<<B_, 128, 0, stream>>>(emb_s, Ws1, bs1, Ws2, bs2, sub_idx, sub_rep);
    k_kgat_mfma<<<(B_ * E_) / G_, 320, 0, stream>>>(ent_emb, ne, nr, Bp, a1b, A2, We1, be1, he);
    k_entity<<<B_, 128, 0, stream>>>(he, Wg, bg, entity_rep);
    k_fuse<<<B_, 256, 0, stream>>>(word_rep, entity_rep, cat_rep, sub_rep, Wfa, bfa, qfa, out);
    k_bn<<<MD_, 256, 0, stream>>>(out, gamma, beta);
}